// Round 1
// baseline (278.503 us; speedup 1.0000x reference)
//
#include <hip/hip_runtime.h>

// nonlocal_channel_similarity: B=16, C=256, H=W=64 (N=HW=4096)
// Algebraic restructure:
//   G_b = X_b X_b^T  (256x256 Gram, bf16 MFMA, K-split 2)
//   s_b = X_b * 1    (row sums, fused into k_gram J==0 blocks)
//   Q   = gw @ Pw    (batch-independent), E[rj] = gw_rj . pb
//   u_b = Tw s_b, v_b = Pw s_b
//   M_b = Tw G_b ;  g[b,rj] = M_b[r,:].Q[rj,:] + tb_r*(gw_rj.v_b)
//                            + (u_b[r]+N*tb_r)*E[rj] + gb[rj] ; relu
//   out[b,c] = sum_o relu_g[b,o]*dw[c,o] + db[c]

#define CC  256
#define NB  16
#define HWN 4096

typedef __attribute__((ext_vector_type(4))) float f32x4;
typedef __attribute__((ext_vector_type(8))) short bf16x8;

__device__ inline unsigned short f2bf(float f) {
  unsigned u = __float_as_uint(f);
  u += 0x7fff + ((u >> 16) & 1);   // round-to-nearest-even
  return (unsigned short)(u >> 16);
}

// ---------------- Gram + row sums -------------------------------------------
// grid (16 tiles, 2 ksplit, 16 batch), 256 threads.
// Tile (I,J): G[64I..64I+63, 64J..64J+63]. LDS stride 72 bf16 breaks bank
// conflicts on ds_read_b128 frag loads (2-way residual aliasing is free).
__global__ __launch_bounds__(256) void k_gram(const float* __restrict__ x,
                                              float* __restrict__ G,
                                              float* __restrict__ S) {
  const int tile = blockIdx.x, ks = blockIdx.y, b = blockIdx.z;
  const int I = tile >> 2, J = tile & 3;
  const float* xb = x + (size_t)b * CC * HWN;
  const float* xa = xb + (size_t)(64 * I) * HWN;
  const float* xB = xb + (size_t)(64 * J) * HWN;

  __shared__ unsigned short As[64 * 72];
  __shared__ unsigned short Bs[64 * 72];

  const int tid = threadIdx.x;
  const int wave = tid >> 6, lane = tid & 63;
  const int lr = tid >> 4;          // staging row base 0..15
  const int c4 = (tid & 15) << 2;   // staging col offset (floats)

  f32x4 acc[4];
  #pragma unroll
  for (int i = 0; i < 4; ++i) acc[i] = (f32x4){0.f, 0.f, 0.f, 0.f};

  float rowsum[4] = {0.f, 0.f, 0.f, 0.f};

  const int k0 = ks * 2048;
  for (int kc = k0; kc < k0 + 2048; kc += 64) {
    __syncthreads();
    #pragma unroll
    for (int p = 0; p < 4; ++p) {
      const int row = p * 16 + lr;
      float4 av = *(const float4*)(xa + (size_t)row * HWN + kc + c4);
      float4 bv = *(const float4*)(xB + (size_t)row * HWN + kc + c4);
      if (J == 0) rowsum[p] += av.x + av.y + av.z + av.w;
      *(ushort4*)&As[row * 72 + c4] =
          make_ushort4(f2bf(av.x), f2bf(av.y), f2bf(av.z), f2bf(av.w));
      *(ushort4*)&Bs[row * 72 + c4] =
          make_ushort4(f2bf(bv.x), f2bf(bv.y), f2bf(bv.z), f2bf(bv.w));
    }
    __syncthreads();
    #pragma unroll
    for (int kk = 0; kk < 64; kk += 32) {
      const int fo = kk + ((lane >> 4) << 3);
      bf16x8 af = *(const bf16x8*)&As[(16 * wave + (lane & 15)) * 72 + fo];
      #pragma unroll
      for (int ct = 0; ct < 4; ++ct) {
        bf16x8 bfr = *(const bf16x8*)&Bs[(16 * ct + (lane & 15)) * 72 + fo];
        acc[ct] = __builtin_amdgcn_mfma_f32_16x16x32_bf16(af, bfr, acc[ct], 0, 0, 0);
      }
    }
  }

  // C/D layout (m89-verified): col = lane&15, row = (lane>>4)*4 + reg
  float* Gb = G + ((size_t)(ks * NB + b) << 16);
  const int col = lane & 15, quad = lane >> 4;
  #pragma unroll
  for (int ct = 0; ct < 4; ++ct) {
    #pragma unroll
    for (int r = 0; r < 4; ++r) {
      const int grow = 64 * I + 16 * wave + quad * 4 + r;
      const int gcol = 64 * J + 16 * ct + col;
      Gb[grow * 256 + gcol] = acc[ct][r];
    }
  }

  if (J == 0) {
    #pragma unroll
    for (int p = 0; p < 4; ++p) {
      float v = rowsum[p];
      v += __shfl_xor(v, 1);
      v += __shfl_xor(v, 2);
      v += __shfl_xor(v, 4);
      v += __shfl_xor(v, 8);
      if ((lane & 15) == 0)
        S[(ks * NB + b) * 256 + 64 * I + 16 * p + lr] = v;
    }
  }
}

// ---------------- Q = gw @ Pw, E = gw . pb ----------------------------------
__global__ __launch_bounds__(256) void k_pre(const float* __restrict__ gw,
                                             const float* __restrict__ pw,
                                             const float* __restrict__ pb,
                                             float* __restrict__ Q,
                                             float* __restrict__ E) {
  const int rj = blockIdx.x, tid = threadIdx.x;
  __shared__ float sm[256];
  sm[tid] = gw[rj * 256 + tid];
  __syncthreads();
  float q = 0.f;
  for (int p = 0; p < 256; ++p) q += sm[p] * pw[p * 256 + tid];
  Q[rj * 256 + tid] = q;
  const float e = sm[tid] * pb[tid];
  __syncthreads();
  sm[tid] = e;
  __syncthreads();
  for (int s = 128; s > 0; s >>= 1) {
    if (tid < s) sm[tid] += sm[tid + s];
    __syncthreads();
  }
  if (tid == 0) E[rj] = sm[0];
}

// ---------------- u = Tw s, v = Pw s ----------------------------------------
__global__ __launch_bounds__(256) void k_sv(const float* __restrict__ S,
                                            const float* __restrict__ tw,
                                            const float* __restrict__ pw,
                                            float* __restrict__ U,
                                            float* __restrict__ V) {
  const int b = blockIdx.x, tid = threadIdx.x;
  __shared__ float sb[256];
  sb[tid] = S[b * 256 + tid] + S[(NB + b) * 256 + tid];
  __syncthreads();
  float u = 0.f, v = 0.f;
  for (int c = 0; c < 256; ++c) {
    const float sc = sb[c];
    u += tw[tid * 256 + c] * sc;
    v += pw[tid * 256 + c] * sc;
  }
  U[b * 256 + tid] = u;
  V[b * 256 + tid] = v;
}

// ---------------- M rows + fused g/relu -------------------------------------
// grid (16 row-chunks, 16 batch), 256 threads. Phase 1: M[16][256] fp32 in
// registers (thread = column c', Tw reads are wave-uniform -> scalar loads).
// Phase 2: 32 outputs/block, 8 lanes per 256-dot, shuffle reduce.
__global__ __launch_bounds__(256) void k_g(const float* __restrict__ G,
                                           const float* __restrict__ tw,
                                           const float* __restrict__ Q,
                                           const float* __restrict__ gw,
                                           const float* __restrict__ V,
                                           const float* __restrict__ U,
                                           const float* __restrict__ E,
                                           const float* __restrict__ tb,
                                           const float* __restrict__ gb,
                                           float* __restrict__ GR) {
  const int rc = blockIdx.x, b = blockIdx.y, tid = threadIdx.x;
  const int r0 = rc * 16;
  __shared__ float Ms[16 * 256];
  const float* G0 = G + ((size_t)b << 16);
  const float* G1 = G + ((size_t)(NB + b) << 16);

  float acc[16];
  #pragma unroll
  for (int r = 0; r < 16; ++r) acc[r] = 0.f;
  for (int c = 0; c < 256; ++c) {
    const float g = G0[c * 256 + tid] + G1[c * 256 + tid];
    #pragma unroll
    for (int r = 0; r < 16; ++r) acc[r] += tw[(r0 + r) * 256 + c] * g;
  }
  #pragma unroll
  for (int r = 0; r < 16; ++r) Ms[r * 256 + tid] = acc[r];
  __syncthreads();

  const int oi = tid >> 3, seg = tid & 7;
  const int rloc = oi >> 1, j = oi & 1;
  const int r = r0 + rloc, rj = r * 2 + j;
  float p1 = 0.f, p2 = 0.f;
  #pragma unroll
  for (int i = 0; i < 32; ++i) {
    const int cp = seg * 32 + i;
    p1 += Ms[rloc * 256 + cp] * Q[rj * 256 + cp];
    p2 += gw[rj * 256 + cp] * V[b * 256 + cp];
  }
  p1 += __shfl_xor(p1, 1); p2 += __shfl_xor(p2, 1);
  p1 += __shfl_xor(p1, 2); p2 += __shfl_xor(p2, 2);
  p1 += __shfl_xor(p1, 4); p2 += __shfl_xor(p2, 4);
  if (seg == 0) {
    const float tbr = tb[r];
    const float gval = p1 + tbr * p2 +
                       (U[b * 256 + r] + 4096.0f * tbr) * E[rj] + gb[rj];
    GR[b * 512 + rj] = fmaxf(gval, 0.f);
  }
}

// ---------------- out = relu_g @ dw^T + db ----------------------------------
__global__ __launch_bounds__(256) void k_out(const float* __restrict__ GR,
                                             const float* __restrict__ dw,
                                             const float* __restrict__ db,
                                             float* __restrict__ out) {
  const int b = blockIdx.x, tid = threadIdx.x;
  __shared__ float gl[512];
  gl[tid] = GR[b * 512 + tid];
  gl[256 + tid] = GR[b * 512 + 256 + tid];
  __syncthreads();
  float a = db[tid];
  for (int o = 0; o < 512; ++o) a += gl[o] * dw[tid * 512 + o];
  out[b * 256 + tid] = a;
}

extern "C" void kernel_launch(void* const* d_in, const int* in_sizes, int n_in,
                              void* d_out, int out_size, void* d_ws, size_t ws_size,
                              hipStream_t stream) {
  const float* x  = (const float*)d_in[0];
  const float* tw = (const float*)d_in[1];
  const float* tb = (const float*)d_in[2];
  const float* pw = (const float*)d_in[3];
  const float* pb = (const float*)d_in[4];
  const float* gw = (const float*)d_in[5];
  const float* gb = (const float*)d_in[6];
  const float* dw = (const float*)d_in[7];
  const float* db = (const float*)d_in[8];
  float* out = (float*)d_out;

  // workspace layout (floats), total ~8.6 MiB
  float* ws = (float*)d_ws;
  float* G  = ws;                       // 2*16*256*256 = 2097152
  float* S  = G + 2 * NB * 65536;       // 2*16*256     = 8192
  float* Q  = S + 2 * NB * 256;         // 512*256      = 131072
  float* E  = Q + 512 * 256;            // 512
  float* U  = E + 512;                  // 16*256
  float* V  = U + NB * 256;             // 16*256
  float* GR = V + NB * 256;             // 16*512

  k_gram<<<dim3(16, 2, 16), 256, 0, stream>>>(x, G, S);
  k_pre<<<512, 256, 0, stream>>>(gw, pw, pb, Q, E);
  k_sv<<<16, 256, 0, stream>>>(S, tw, pw, U, V);
  k_g<<<dim3(16, 16), 256, 0, stream>>>(G, tw, Q, gw, V, U, E, tb, gb, GR);
  k_out<<<16, 256, 0, stream>>>(GR, dw, db, out);
}

// Round 2
// 245.874 us; speedup vs baseline: 1.1327x; 1.1327x over previous
//
#include <hip/hip_runtime.h>

// nonlocal_channel_similarity: B=16, C=256, H=W=64 (N=HW=4096)
//   G_b = X_b X_b^T   (fp32 atomics, 128x128 MFMA tiles, ksplit 4)
//   s_b = rowsums(X_b) (fused into diagonal gram tiles)
//   Q = gw@Pw (bf16), E = gw.pb, u = Tw s, v = Pw s, W2 = gw.v   (k_mid)
//   P''_b = G_b Q^T via MFMA; term[rj] = sum_c Tw[r,c] P''[c,rj]  (k_p, fused)
//   g = relu(term + tb_r*W2 + (u_r + N tb_r)*E + gb)              (k_p epilogue)
//   out = g @ dw^T + db                                            (k_out)

#define CC  256
#define NB  16
#define HWN 4096

typedef __attribute__((ext_vector_type(4))) float f32x4;
typedef __attribute__((ext_vector_type(8))) short bf16x8;

__device__ inline unsigned short f2bf(float f) {
  unsigned u = __float_as_uint(f);
  u += 0x7fff + ((u >> 16) & 1);   // round-to-nearest-even
  return (unsigned short)(u >> 16);
}

// ---------------- zero G (4 MB) + S (16 KB) ---------------------------------
__global__ __launch_bounds__(256) void k_zero(float4* __restrict__ p) {
  p[(size_t)blockIdx.x * 256 + threadIdx.x] = make_float4(0.f, 0.f, 0.f, 0.f);
}

// ---------------- Gram + row sums -------------------------------------------
// grid (4 tiles of 128x128, 4 ksplit, 16 batch), 256 threads / 4 waves.
// Wave w owns rows [32w,32w+32) x all 128 cols: acc[2][8] (64 VGPRs).
// Diagonal tiles stage A only (B==A) and compute row sums.
__global__ __launch_bounds__(256) void k_gram(const float* __restrict__ x,
                                              float* __restrict__ G,
                                              float* __restrict__ S) {
  const int tile = blockIdx.x, ks = blockIdx.y, b = blockIdx.z;
  const int I = tile >> 1, J = tile & 1;
  const bool diag = (I == J);
  const float* xa = x + (size_t)b * CC * HWN + (size_t)(128 * I) * HWN;
  const float* xb = x + (size_t)b * CC * HWN + (size_t)(128 * J) * HWN;

  __shared__ unsigned short As[128 * 72];
  __shared__ unsigned short Bs[128 * 72];

  const int tid = threadIdx.x, w = tid >> 6, lane = tid & 63;
  const int quad = lane >> 4, m15 = lane & 15;
  const int srow = tid >> 4;          // staging row base 0..15
  const int scol = (tid & 15) << 2;   // staging col (floats)

  f32x4 acc[2][8];
  #pragma unroll
  for (int t = 0; t < 2; ++t)
    #pragma unroll
    for (int c = 0; c < 8; ++c) acc[t][c] = (f32x4){0.f, 0.f, 0.f, 0.f};
  float rs[8] = {0.f, 0.f, 0.f, 0.f, 0.f, 0.f, 0.f, 0.f};

  const int k0 = ks * 1024;
  for (int kc = k0; kc < k0 + 1024; kc += 64) {
    __syncthreads();
    #pragma unroll
    for (int p = 0; p < 8; ++p) {
      const int row = p * 16 + srow;
      float4 av = *(const float4*)(xa + (size_t)row * HWN + kc + scol);
      *(ushort4*)&As[row * 72 + scol] =
          make_ushort4(f2bf(av.x), f2bf(av.y), f2bf(av.z), f2bf(av.w));
      if (diag) {
        rs[p] += av.x + av.y + av.z + av.w;
      } else {
        float4 bv = *(const float4*)(xb + (size_t)row * HWN + kc + scol);
        *(ushort4*)&Bs[row * 72 + scol] =
            make_ushort4(f2bf(bv.x), f2bf(bv.y), f2bf(bv.z), f2bf(bv.w));
      }
    }
    __syncthreads();
    const unsigned short* Bbase = diag ? As : Bs;
    #pragma unroll
    for (int kk = 0; kk < 64; kk += 32) {
      const int fo = kk + (quad << 3);
      bf16x8 a0 = *(const bf16x8*)&As[(32 * w + m15) * 72 + fo];
      bf16x8 a1 = *(const bf16x8*)&As[(32 * w + 16 + m15) * 72 + fo];
      #pragma unroll
      for (int ct = 0; ct < 8; ++ct) {
        bf16x8 bf = *(const bf16x8*)&Bbase[(16 * ct + m15) * 72 + fo];
        acc[0][ct] = __builtin_amdgcn_mfma_f32_16x16x32_bf16(a0, bf, acc[0][ct], 0, 0, 0);
        acc[1][ct] = __builtin_amdgcn_mfma_f32_16x16x32_bf16(a1, bf, acc[1][ct], 0, 0, 0);
      }
    }
  }

  // C/D layout: col = lane&15, row = quad*4 + reg (m89-verified)
  float* Gb = G + ((size_t)b << 16);
  #pragma unroll
  for (int t = 0; t < 2; ++t)
    #pragma unroll
    for (int ct = 0; ct < 8; ++ct)
      #pragma unroll
      for (int r = 0; r < 4; ++r) {
        const int gi = 128 * I + 32 * w + 16 * t + quad * 4 + r;
        const int gj = 128 * J + 16 * ct + m15;
        atomicAdd(&Gb[gi * 256 + gj], acc[t][ct][r]);
      }

  if (diag) {
    #pragma unroll
    for (int p = 0; p < 8; ++p) {
      float v = rs[p];
      v += __shfl_xor(v, 1);
      v += __shfl_xor(v, 2);
      v += __shfl_xor(v, 4);
      v += __shfl_xor(v, 8);
      if ((tid & 15) == 0)
        atomicAdd(&S[b * 256 + 128 * I + p * 16 + srow], v);
    }
  }
}

// ---------------- small matvecs: Q(bf16), E, u, v, W2 -----------------------
// blocks 0..511: Q row rj + E[rj].  blocks 512..527: per-batch u, v, W2.
__global__ __launch_bounds__(256) void k_mid(const float* __restrict__ gw,
                                             const float* __restrict__ pw,
                                             const float* __restrict__ pb,
                                             const float* __restrict__ tw,
                                             const float* __restrict__ S,
                                             unsigned short* __restrict__ Qh,
                                             float* __restrict__ E,
                                             float* __restrict__ U,
                                             float* __restrict__ W2) {
  __shared__ float sm[512];
  const int tid = threadIdx.x, blk = blockIdx.x;
  if (blk < 512) {
    const int rj = blk;
    sm[tid] = gw[rj * 256 + tid];
    __syncthreads();
    float q = 0.f;
    for (int p = 0; p < 256; ++p) q += sm[p] * pw[p * 256 + tid];
    Qh[rj * 256 + tid] = f2bf(q);
    sm[256 + tid] = sm[tid] * pb[tid];
    __syncthreads();
    for (int s = 128; s > 0; s >>= 1) {
      if (tid < s) sm[256 + tid] += sm[256 + tid + s];
      __syncthreads();
    }
    if (tid == 0) E[rj] = sm[256];
  } else {
    const int b = blk - 512;
    sm[tid] = S[b * 256 + tid];
    __syncthreads();
    float u = 0.f, v = 0.f;
    for (int k = 0; k < 256; ++k) {
      const float sk = sm[k];
      u += tw[tid * 256 + k] * sk;
      v += pw[tid * 256 + k] * sk;
    }
    U[b * 256 + tid] = u;
    __syncthreads();
    sm[256 + tid] = v;
    __syncthreads();
    #pragma unroll
    for (int pass = 0; pass < 2; ++pass) {
      const int rj = pass * 256 + tid;
      float w2 = 0.f;
      for (int c = 0; c < 256; ++c) w2 += gw[rj * 256 + c] * sm[256 + c];
      W2[b * 512 + rj] = w2;
    }
  }
}

// ---------------- P'' = G_b Q^T + fused Tw-contraction/bias/relu ------------
// grid (16 rj-tiles of 32, 16 batch), 256 thr / 4 waves.
// Wave w: m-rows c in [64w,64w+64) (4 m-tiles) x 2 n-tiles (rj). K = 256.
// Frags load DIRECTLY from global (L2-resident): G fp32->bf16 in-register.
__global__ __launch_bounds__(256) void k_p(const float* __restrict__ G,
                                           const unsigned short* __restrict__ Qh,
                                           const float* __restrict__ tw,
                                           const float* __restrict__ U,
                                           const float* __restrict__ W2,
                                           const float* __restrict__ E,
                                           const float* __restrict__ tb,
                                           const float* __restrict__ gb,
                                           float* __restrict__ GR) {
  const int rjt = blockIdx.x, b = blockIdx.y;
  const int rj0 = rjt * 32;
  const int tid = threadIdx.x, w = tid >> 6, lane = tid & 63;
  const int quad = lane >> 4, m15 = lane & 15;
  const float* Gb = G + ((size_t)b << 16);

  f32x4 acc[4][2];
  #pragma unroll
  for (int mt = 0; mt < 4; ++mt) {
    acc[mt][0] = (f32x4){0.f, 0.f, 0.f, 0.f};
    acc[mt][1] = (f32x4){0.f, 0.f, 0.f, 0.f};
  }

  #pragma unroll
  for (int s = 0; s < 8; ++s) {
    const int kb = s * 32 + quad * 8;
    bf16x8 bq0 = *(const bf16x8*)(Qh + (rj0 + m15) * 256 + kb);
    bf16x8 bq1 = *(const bf16x8*)(Qh + (rj0 + 16 + m15) * 256 + kb);
    #pragma unroll
    for (int mt = 0; mt < 4; ++mt) {
      const float* ap = Gb + (64 * w + 16 * mt + m15) * 256 + kb;
      float4 g0 = *(const float4*)ap;
      float4 g1 = *(const float4*)(ap + 4);
      bf16x8 ag;
      ag[0] = (short)f2bf(g0.x); ag[1] = (short)f2bf(g0.y);
      ag[2] = (short)f2bf(g0.z); ag[3] = (short)f2bf(g0.w);
      ag[4] = (short)f2bf(g1.x); ag[5] = (short)f2bf(g1.y);
      ag[6] = (short)f2bf(g1.z); ag[7] = (short)f2bf(g1.w);
      acc[mt][0] = __builtin_amdgcn_mfma_f32_16x16x32_bf16(ag, bq0, acc[mt][0], 0, 0, 0);
      acc[mt][1] = __builtin_amdgcn_mfma_f32_16x16x32_bf16(ag, bq1, acc[mt][1], 0, 0, 0);
    }
  }

  // epilogue: term[rj] = sum_c P''[c,rj] * Tw[r,c]
  // C/D: col(rj within tile) = m15, row(c within tile) = quad*4+reg
  __shared__ float sred[32 * 4];
  #pragma unroll
  for (int nt = 0; nt < 2; ++nt) {
    const int rj = rj0 + 16 * nt + m15;
    const int r = rj >> 1;
    float p = 0.f;
    #pragma unroll
    for (int mt = 0; mt < 4; ++mt)
      #pragma unroll
      for (int reg = 0; reg < 4; ++reg)
        p += acc[mt][nt][reg] * tw[r * 256 + 64 * w + 16 * mt + quad * 4 + reg];
    p += __shfl_xor(p, 16);
    p += __shfl_xor(p, 32);
    if (quad == 0) sred[(16 * nt + m15) * 4 + w] = p;
  }
  __syncthreads();
  if (tid < 32) {
    const int rj = rj0 + tid, r = rj >> 1;
    const float v = sred[tid * 4] + sred[tid * 4 + 1] +
                    sred[tid * 4 + 2] + sred[tid * 4 + 3];
    const float tbr = tb[r];
    const float bias = tbr * W2[b * 512 + rj] +
                       (U[b * 256 + r] + 4096.0f * tbr) * E[rj] + gb[rj];
    GR[b * 512 + rj] = fmaxf(v + bias, 0.f);
  }
}

// ---------------- out = relu_g @ dw^T + db ----------------------------------
// grid (16 c-chunks, 16 b): 16 threads per output, coalesced dw reads.
__global__ __launch_bounds__(256) void k_out(const float* __restrict__ GR,
                                             const float* __restrict__ dw,
                                             const float* __restrict__ db,
                                             float* __restrict__ out) {
  const int cch = blockIdx.x, b = blockIdx.y, tid = threadIdx.x;
  __shared__ float gl[512];
  gl[tid] = GR[b * 512 + tid];
  gl[256 + tid] = GR[b * 512 + 256 + tid];
  __syncthreads();
  const int cl = tid >> 4, l = tid & 15;
  const int c = cch * 16 + cl;
  float a = 0.f;
  #pragma unroll 8
  for (int i = 0; i < 32; ++i) {
    const int o = i * 16 + l;
    a += gl[o] * dw[c * 512 + o];
  }
  a += __shfl_xor(a, 1);
  a += __shfl_xor(a, 2);
  a += __shfl_xor(a, 4);
  a += __shfl_xor(a, 8);
  if (l == 0) out[b * 256 + c] = a + db[c];
}

extern "C" void kernel_launch(void* const* d_in, const int* in_sizes, int n_in,
                              void* d_out, int out_size, void* d_ws, size_t ws_size,
                              hipStream_t stream) {
  const float* x  = (const float*)d_in[0];
  const float* tw = (const float*)d_in[1];
  const float* tb = (const float*)d_in[2];
  const float* pw = (const float*)d_in[3];
  const float* pb = (const float*)d_in[4];
  const float* gw = (const float*)d_in[5];
  const float* gb = (const float*)d_in[6];
  const float* dw = (const float*)d_in[7];
  const float* db = (const float*)d_in[8];
  float* out = (float*)d_out;

  // workspace layout (floats): total ~4.6 MB
  float* ws = (float*)d_ws;
  float* G  = ws;                                // 16*65536      = 1048576
  float* S  = G + NB * 65536;                    // 16*256        = 4096
  float* Qf = S + NB * 256;                      // Qh: 512*256 bf16 (65536 f)
  unsigned short* Qh = (unsigned short*)Qf;
  float* E  = Qf + 65536;                        // 512
  float* U  = E + 512;                           // 16*256 = 4096
  float* W2 = U + NB * 256;                      // 16*512 = 8192
  float* GR = W2 + NB * 512;                     // 16*512 = 8192

  // zero G + S: (1048576 + 4096) floats = 263168 float4 = 1028 blocks * 256
  k_zero<<<1028, 256, 0, stream>>>((float4*)ws);
  k_gram<<<dim3(4, 4, NB), 256, 0, stream>>>(x, G, S);
  k_mid<<<528, 256, 0, stream>>>(gw, pw, pb, tw, S, Qh, E, U, W2);
  k_p<<<dim3(16, NB), 256, 0, stream>>>(G, Qh, tw, U, W2, E, tb, gb, GR);
  k_out<<<dim3(16, NB), 256, 0, stream>>>(GR, dw, db, out);
}